// Round 2
// baseline (57.218 us; speedup 1.0000x reference)
//
#include <hip/hip_runtime.h>
#include <math.h>

#define NCLS 19
#define ACTC 18      // classes 1..18 contribute
#define BINS 51
#define NPIX 4096
#define NFEAT 256
#define CHUNKS 64    // NPIX / 64
#define TWO_PI_F 6.2831853071795864769f

// ws layout:
//   float partial[ACTC*NFEAT]   @ 0        (18432 B)
//   int   base[NCLS+1] (pad 32) @ 18432
//   int   idx[NPIX]             @ 18560

// ---------------- kernel 0: deterministic class bucketing ----------------
__global__ __launch_bounds__(256)
void bucket_k(const int* __restrict__ lab, int* __restrict__ base_g,
              int* __restrict__ idx_g) {
    __shared__ int cnt[CHUNKS][NCLS];   // chunk-level counts -> chunk prefix
    __shared__ int base_s[NCLS + 1];
    const int tid  = threadIdx.x;
    const int lane = tid & 63;
    const int wave = tid >> 6;

    // pass 1: per-chunk per-class counts via ballot (deterministic)
    for (int ch = wave; ch < CHUNKS; ch += 4) {
        int v = lab[ch * 64 + lane];
        for (int c = 1; c < NCLS; ++c) {
            unsigned long long m = __ballot(v == c);
            if (lane == 0) cnt[ch][c] = (int)__popcll(m);
        }
    }
    __syncthreads();

    // pass 2: per-class exclusive prefix over chunks (one thread per class)
    if (tid >= 1 && tid < NCLS) {
        const int c = tid;
        int run = 0;
        for (int ch = 0; ch < CHUNKS; ++ch) {
            int t = cnt[ch][c];
            cnt[ch][c] = run;
            run += t;
        }
        base_s[c] = run;                 // per-class total (temporarily)
    }
    __syncthreads();
    if (tid == 0) {
        int run = 0;
        base_s[0] = 0;
        for (int c = 1; c < NCLS; ++c) { int t = base_s[c]; base_s[c] = run; run += t; }
        base_s[NCLS] = run;
        for (int c = 0; c <= NCLS; ++c) base_g[c] = base_s[c];
    }
    __syncthreads();

    // pass 3: rank-based placement (deterministic order: chunk-major, lane order)
    for (int ch = wave; ch < CHUNKS; ch += 4) {
        int p = ch * 64 + lane;
        int v = lab[p];
        for (int c = 1; c < NCLS; ++c) {
            unsigned long long m = __ballot(v == c);
            if (v == c) {
                int rank = (int)__popcll(m & ((1ull << lane) - 1ull));
                idx_g[base_s[c] + cnt[ch][c] + rank] = p;
            }
        }
    }
}

// ---------------- kernel 1: per-(feature,class) KDE + smooth-L1 ----------------
__global__ __launch_bounds__(256)
void hist_main(const float* __restrict__ x, const int* __restrict__ base_g,
               const int* __restrict__ idx_g, float* __restrict__ partial) {
    const int f    = blockIdx.x;
    const int c    = blockIdx.y + 1;
    const int tid  = threadIdx.x;
    const int lane = tid & 63;
    const int wave = tid >> 6;

    __shared__ __align__(16) float xs[NPIX];
    __shared__ float s_red[8];
    __shared__ float s_acc[4][64];

    const int st = base_g[c];
    const int n  = base_g[c + 1] - st;
    if (n == 0) {
        if (tid == 0) partial[blockIdx.y * NFEAT + f] = 0.0f;
        return;
    }

    // gather this class's x values (scattered L2-resident reads) + stats
    const float* xrow = x + (size_t)f * NPIX;
    float s1 = 0.f, s2 = 0.f;
    for (int i = tid; i < n; i += 256) {
        float v = xrow[idx_g[st + i]];
        xs[i] = v;
        s1 += v; s2 += v * v;
    }
    for (int off = 32; off; off >>= 1) {
        s1 += __shfl_down(s1, off, 64);
        s2 += __shfl_down(s2, off, 64);
    }
    if (lane == 0) { s_red[wave] = s1; s_red[4 + wave] = s2; }
    __syncthreads();

    const float sum1 = s_red[0] + s_red[1] + s_red[2] + s_red[3];
    const float sum2 = s_red[4] + s_red[5] + s_red[6] + s_red[7];
    const float fn   = (float)n;
    const float miu  = sum1 / fn;
    const float var  = fmaxf(sum2 / fn - miu * miu, 1e-12f);
    const float var_s = var * 0.04f;       // var / 25

    // KDE: lane <-> bin; waves split pixels; float4 + 4 exp chains for ILP
    const float binv = -5.0f + 0.2f * (float)lane;
    const float coef = -0.5f / var_s;
    float a0 = 0.f, a1 = 0.f, a2 = 0.f, a3 = 0.f;
    const int nv = n & ~3;
    for (int i = wave * 4; i < nv; i += 16) {
        float4 v = *(const float4*)&xs[i];
        float d0 = binv - v.x, d1 = binv - v.y, d2 = binv - v.z, d3 = binv - v.w;
        a0 += __expf(coef * d0 * d0);
        a1 += __expf(coef * d1 * d1);
        a2 += __expf(coef * d2 * d2);
        a3 += __expf(coef * d3 * d3);
    }
    for (int i = nv + wave; i < n; i += 4) {   // tail (<4 elements)
        float d = binv - xs[i];
        a0 += __expf(coef * d * d);
    }
    float acc = (a0 + a1) + (a2 + a3);
    if (lane >= BINS) acc = 0.f;
    s_acc[wave][lane] = acc;
    __syncthreads();

    if (wave == 0) {
        float kde = s_acc[0][lane] + s_acc[1][lane] + s_acc[2][lane] + s_acc[3][lane];
        float dt  = binv - miu;
        float tg  = __expf((-0.5f / var) * dt * dt);
        if (lane >= BINS) { kde = 0.f; tg = 0.f; }

        const float inv_s_vs = rsqrtf(TWO_PI_F * var_s);
        const float inv_s_v  = rsqrtf(TWO_PI_F * var);
        float sv = kde * inv_s_vs;
        float tt = tg  * inv_s_v;

        float ssum = sv, tsum = tt;
        for (int off = 32; off; off >>= 1) {
            ssum += __shfl_xor(ssum, off, 64);
            tsum += __shfl_xor(tsum, off, 64);
        }
        float hist  = sv / fmaxf(ssum, 1e-12f);
        float tnorm = tt / tsum;
        float diff  = hist - tnorm;
        float ad    = fabsf(diff);
        float sl1   = (ad < 1.0f) ? 0.5f * diff * diff : (ad - 0.5f);
        if (lane >= BINS) sl1 = 0.f;
        for (int off = 32; off; off >>= 1) sl1 += __shfl_xor(sl1, off, 64);
        if (lane == 0) partial[blockIdx.y * NFEAT + f] = sl1;
    }
}

// ---------------- kernel 2: deterministic final reduction ----------------
__global__ __launch_bounds__(256)
void hist_final(const float* __restrict__ partial, const int* __restrict__ base_g,
                float* __restrict__ out) {
    const int tid  = threadIdx.x;
    const int lane = tid & 63;
    const int wave = tid >> 6;
    __shared__ double sd[4];

    double s = 0.0;
    for (int i = tid; i < ACTC * NFEAT; i += 256) s += (double)partial[i];
    for (int off = 32; off; off >>= 1) s += __shfl_down(s, off, 64);
    if (lane == 0) sd[wave] = s;
    __syncthreads();
    if (tid == 0) {
        double tot = sd[0] + sd[1] + sd[2] + sd[3];
        int active = 0;
        for (int c = 1; c < NCLS; ++c) active += (base_g[c + 1] - base_g[c] > 0) ? 1 : 0;
        double loss = tot / (double)(NFEAT * BINS);
        loss = loss / ((double)active + 1e-12);
        out[0] = (float)loss;
    }
}

extern "C" void kernel_launch(void* const* d_in, const int* in_sizes, int n_in,
                              void* d_out, int out_size, void* d_ws, size_t ws_size,
                              hipStream_t stream) {
    const float* x   = (const float*)d_in[0];
    const int*   lab = (const int*)d_in[1];
    float* out       = (float*)d_out;
    float* partial   = (float*)d_ws;
    int*   base_g    = (int*)((char*)d_ws + (size_t)ACTC * NFEAT * sizeof(float));
    int*   idx_g     = (int*)((char*)d_ws + (size_t)ACTC * NFEAT * sizeof(float) + 128);

    hipLaunchKernelGGL(bucket_k, dim3(1), dim3(256), 0, stream, lab, base_g, idx_g);
    hipLaunchKernelGGL(hist_main, dim3(NFEAT, ACTC), dim3(256), 0, stream,
                       x, base_g, idx_g, partial);
    hipLaunchKernelGGL(hist_final, dim3(1), dim3(256), 0, stream, partial, base_g, out);
}